// Round 2
// baseline (738.762 us; speedup 1.0000x reference)
//
#include <hip/hip_runtime.h>
#include <hip/hip_bf16.h>

typedef __attribute__((ext_vector_type(4))) float f4v;
typedef __attribute__((ext_vector_type(8))) short bf8v;

// ---- problem constants ----
#define NPOS 32768            // 32*32*32
#define CCH  192
#define HID  768

// ---- workspace layout (bytes) ----
#define WS_Y    ((size_t)0)           // 2*192*32768*2 = 25,165,824  conv out bf16 NCDHW
#define WS_B1F  ((size_t)25165824)    // 294,912  w1 bf16 B-frag swizzled
#define WS_B2F  ((size_t)25460736)    // 294,912  w2 bf16 B-frag swizzled
#define WS_LNA  ((size_t)25755648)    // 1024*12288*2 = 25,165,824  LN out bf16 A-frag
// total: 50,921,472 bytes

__device__ inline unsigned short f2bf(float f){
  unsigned int u = __float_as_uint(f);
  u += 0x7FFFu + ((u >> 16) & 1u);      // RNE
  return (unsigned short)(u >> 16);
}
__device__ inline float bf2f(unsigned short s){
  return __uint_as_float(((unsigned int)s) << 16);
}
__device__ inline float gelu_f(float x){
  float u = 0.7978845608028654f * x * fmaf(0.044715f, x*x, 1.0f);
  float e = __expf(2.0f*u);
  float th = __fdividef(e - 1.0f, e + 1.0f);
  return 0.5f*x*(1.0f + th);
}

// ---------------------------------------------------------------------------
// Kernel 1: depthwise 7x7x7 conv + bias, channels-first, z-streamed LDS ring.
// Block = (batch, y-half, channel). 256 threads = (tx:8, ty:16, tz:2).
// Thread computes 4x * 1y * 2z outputs per z-step (8 steps of 4 z).
// LDS ring: 10 slices of 22 rows x 40 floats (35.2 KB). Dense (no mask).
// Writes y bf16 NCDHW.
// ---------------------------------------------------------------------------
__global__ __launch_bounds__(256) void conv_dw_kernel(
    const float* __restrict__ x, const float* __restrict__ dw_w,
    const float* __restrict__ dw_b, unsigned short* __restrict__ yb)
{
  __shared__ float ring[10][22][40];

  int bid = blockIdx.x;                 // 768 = 2b * 2yh * 192c
  int c  = bid % 192;
  int rb = bid / 192;
  int yh = rb & 1, b = rb >> 1;
  int ybase = yh * 16;

  int tid = threadIdx.x;
  int tx = tid & 7, ty = (tid >> 3) & 15, tz = tid >> 7;
  int tx4 = tx * 4;

  const float* xsrc = x + (size_t)(b*CCH + c)*NPOS;
  const float* dwc  = dw_w + c*343;
  float bias = dw_b[c];

  // ---- initial stage: slices zi = -3..6 into slots 0..9
  for (int sl = 0; sl < 10; ++sl) {
    int zi = sl - 3;
    for (int k = 0; k < 4; ++k) {
      int idx = tid + 256*k;
      if (idx < 836) {                      // 22*38
        int r  = idx / 38, xr = idx - r*38;
        int yg = ybase - 3 + r, xg = xr - 3;
        float v = 0.f;
        if ((unsigned)zi < 32u && (unsigned)yg < 32u && (unsigned)xg < 32u)
          v = xsrc[(size_t)zi*1024 + yg*32 + xg];
        ring[sl][r][xr] = v;
      }
    }
  }
  __syncthreads();

  unsigned short* yout = yb + (size_t)(b*CCH + c)*NPOS
                            + (size_t)(ybase + ty)*32 + tx4;

  for (int zo = 0; zo < 32; zo += 4) {
    // ---- prefetch next 4 slices (zi = zo+7 .. zo+10) into registers
    float pre[4][4];
    if (zo < 28) {
      #pragma unroll
      for (int j = 0; j < 4; ++j) {
        int zi = zo + 7 + j;
        #pragma unroll
        for (int k = 0; k < 4; ++k) {
          int idx = tid + 256*k;
          float v = 0.f;
          if (idx < 836) {
            int r  = idx / 38, xr = idx - r*38;
            int yg = ybase - 3 + r, xg = xr - 3;
            if ((unsigned)zi < 32u && (unsigned)yg < 32u && (unsigned)xg < 32u)
              v = xsrc[(size_t)zi*1024 + yg*32 + xg];
          }
          pre[j][k] = v;
        }
      }
    }

    // ---- compute: outputs z in {zo+2tz, zo+2tz+1}
    float acc0[4] = {0.f,0.f,0.f,0.f};
    float acc1[4] = {0.f,0.f,0.f,0.f};
    int m0 = (zo + 2*tz) % 10;            // slot of zi = zo+2tz-3

    for (int q = 0; q < 8; ++q) {         // zi = zo+2tz-3+q
      int s = m0 + q; if (s >= 10) s -= 10;
      const float* slp = &ring[s][ty][tx4];
      #pragma unroll
      for (int ky = 0; ky < 7; ++ky) {
        const float* rp = slp + ky*40;
        f4v r0 = *(const f4v*)rp;
        f4v r1 = *(const f4v*)(rp + 4);
        f4v r2 = *(const f4v*)(rp + 8);
        float row[12];
        row[0]=r0[0]; row[1]=r0[1]; row[2]=r0[2]; row[3]=r0[3];
        row[4]=r1[0]; row[5]=r1[1]; row[6]=r1[2]; row[7]=r1[3];
        row[8]=r2[0]; row[9]=r2[1]; row[10]=r2[2]; row[11]=r2[3];
        if (q != 7) {                     // out0: kz = q
          const float* wb = dwc + q*49 + ky*7;
          #pragma unroll
          for (int kx = 0; kx < 7; ++kx) {
            float w = wb[kx];
            #pragma unroll
            for (int xo = 0; xo < 4; ++xo)
              acc0[xo] = fmaf(w, row[kx+xo], acc0[xo]);
          }
        }
        if (q != 0) {                     // out1: kz = q-1
          const float* wb = dwc + (q-1)*49 + ky*7;
          #pragma unroll
          for (int kx = 0; kx < 7; ++kx) {
            float w = wb[kx];
            #pragma unroll
            for (int xo = 0; xo < 4; ++xo)
              acc1[xo] = fmaf(w, row[kx+xo], acc1[xo]);
          }
        }
      }
    }

    // ---- store 2 x ushort4 (bf16)
    {
      int z0v = zo + 2*tz;
      ushort4 p0, p1;
      p0.x = f2bf(acc0[0]+bias); p0.y = f2bf(acc0[1]+bias);
      p0.z = f2bf(acc0[2]+bias); p0.w = f2bf(acc0[3]+bias);
      p1.x = f2bf(acc1[0]+bias); p1.y = f2bf(acc1[1]+bias);
      p1.z = f2bf(acc1[2]+bias); p1.w = f2bf(acc1[3]+bias);
      *(ushort4*)(yout + (size_t)z0v*1024)     = p0;
      *(ushort4*)(yout + (size_t)(z0v+1)*1024) = p1;
    }

    // ---- commit prefetched slices into ring
    __syncthreads();
    if (zo < 28) {
      int mz = zo % 10;
      #pragma unroll
      for (int j = 0; j < 4; ++j) {
        int s = mz + j; if (s >= 10) s -= 10;
        #pragma unroll
        for (int k = 0; k < 4; ++k) {
          int idx = tid + 256*k;
          if (idx < 836) {
            int r = idx / 38, xr = idx - r*38;
            ring[s][r][xr] = pre[j][k];
          }
        }
      }
      __syncthreads();
    }
  }
}

// ---------------------------------------------------------------------------
// Kernel 2: weight prep. w1/w2 -> bf16 MFMA-B-fragment order.
// B-frag (16x16x32): element (k,n) -> lane=((k%32)/8)*16+(n%16), byte j=k%8.
// ---------------------------------------------------------------------------
__global__ __launch_bounds__(256) void prep_w_kernel(
    const float* __restrict__ w1, const float* __restrict__ w2,
    unsigned short* __restrict__ b1f, unsigned short* __restrict__ b2f)
{
  int gid = blockIdx.x*256 + threadIdx.x;
  if (gid < 18432) {
    int fi = gid;                         // w1 (C=192 x HID=768)
    int lane = fi & 63, fr = fi >> 6;
    int nt = fr / 6, ks = fr - nt*6;      // ntile 0..47, kstep 0..5
    int n  = nt*16 + (lane & 15);
    int kb = ks*32 + (lane >> 4)*8;
    #pragma unroll
    for (int j = 0; j < 8; ++j) b1f[fi*8 + j] = f2bf(w1[(kb+j)*HID + n]);
  } else if (gid < 36864) {
    int fi = gid - 18432;                 // w2 (HID=768 x C=192)
    int lane = fi & 63, fr = fi >> 6;
    int nt = fr / 24, ks = fr - nt*24;    // ntile 0..11, kstep 0..23
    int n  = nt*16 + (lane & 15);
    int kb = ks*32 + (lane >> 4)*8;
    #pragma unroll
    for (int j = 0; j < 8; ++j) b2f[fi*8 + j] = f2bf(w2[(kb+j)*CCH + n]);
  }
}

// ---------------------------------------------------------------------------
// Kernel 3: per-cell LayerNorm over channels (active cells) + zero-fill of
// d_out for inactive cells. Reads y bf16, writes lnA in MFMA A-frag order.
// 1024 blocks x 384 threads = (p4:16 [dz,dy], cg:24 [8 channels each]).
// ---------------------------------------------------------------------------
__global__ __launch_bounds__(384) void ln_kernel(
    const unsigned short* __restrict__ yb, const float* __restrict__ ln_w,
    const float* __restrict__ ln_b, const int* __restrict__ mask,
    unsigned short* __restrict__ lnA, float* __restrict__ out)
{
  int bid = blockIdx.x;
  int b = bid >> 9, cell = bid & 511;
  int cz = cell >> 6, cy = (cell >> 3) & 7, cx = cell & 7;
  int z0 = cz*4, y0 = cy*4, x0 = cx*4;
  int tid = threadIdx.x;

  if (mask[bid] == 0) {
    f4v z4 = {0.f,0.f,0.f,0.f};
    #pragma unroll
    for (int p = 0; p < 8; ++p) {
      int i4 = tid + 384*p;               // 0..3071
      int c = i4 >> 4, rem = i4 & 15;
      int dz = rem >> 2, dy = rem & 3;
      size_t off = ((size_t)(b*CCH + c))*NPOS + (size_t)(z0+dz)*1024 + (y0+dy)*32 + x0;
      *(f4v*)(out + off) = z4;
    }
    return;
  }

  int p4 = tid & 15, cg = tid >> 4;       // p4 = dz*4+dy ; cg 0..23
  int dz = p4 >> 2, dy = p4 & 3;
  size_t posoff = (size_t)(z0+dz)*1024 + (y0+dy)*32 + x0;

  float v[8][4];
  float s[4] = {0,0,0,0}, qq[4] = {0,0,0,0};
  #pragma unroll
  for (int j = 0; j < 8; ++j) {
    int c = cg*8 + j;
    ushort4 u = *(const ushort4*)(yb + (size_t)(b*CCH + c)*NPOS + posoff);
    float f0 = bf2f(u.x), f1 = bf2f(u.y), f2 = bf2f(u.z), f3 = bf2f(u.w);
    v[j][0]=f0; v[j][1]=f1; v[j][2]=f2; v[j][3]=f3;
    s[0]+=f0; s[1]+=f1; s[2]+=f2; s[3]+=f3;
    qq[0]+=f0*f0; qq[1]+=f1*f1; qq[2]+=f2*f2; qq[3]+=f3*f3;
  }
  // reduce over cg: lanes p4, p4+16, p4+32, p4+48 within wave, then 6 waves
  #pragma unroll
  for (int k = 0; k < 4; ++k) {
    s[k]  += __shfl_xor(s[k], 16, 64);  s[k]  += __shfl_xor(s[k], 32, 64);
    qq[k] += __shfl_xor(qq[k], 16, 64); qq[k] += __shfl_xor(qq[k], 32, 64);
  }
  __shared__ float red[6][16][8];
  int wv = tid >> 6, lane = tid & 63;
  if (lane < 16) {
    #pragma unroll
    for (int k = 0; k < 4; ++k) { red[wv][lane][k] = s[k]; red[wv][lane][4+k] = qq[k]; }
  }
  __syncthreads();

  float mu[4], rs[4];
  #pragma unroll
  for (int k = 0; k < 4; ++k) {
    float S = 0.f, Q = 0.f;
    #pragma unroll
    for (int w = 0; w < 6; ++w) { S += red[w][p4][k]; Q += red[w][p4][4+k]; }
    float m = S * (1.f/192.f);
    float var = Q * (1.f/192.f) - m*m;
    mu[k] = m; rs[k] = rsqrtf(var + 1e-6f);
  }

  float lw[8], lb[8];
  #pragma unroll
  for (int j = 0; j < 8; ++j) { lw[j] = ln_w[cg*8+j]; lb[j] = ln_b[cg*8+j]; }

  unsigned short* dst = lnA + (size_t)bid*12288;
  // elem(T,c) = (((T>>4)*6 + (c>>5))*64 + ((c>>3)&3)*16 + (T&15))*8 + (c&7)
  #pragma unroll
  for (int k = 0; k < 4; ++k) {
    int T = p4*4 + k;                     // dz*16 + dy*4 + dx
    unsigned int pk[4];
    #pragma unroll
    for (int jp = 0; jp < 4; ++jp) {
      float a = (v[2*jp][k]   - mu[k])*rs[k]*lw[2*jp]   + lb[2*jp];
      float bqv = (v[2*jp+1][k] - mu[k])*rs[k]*lw[2*jp+1] + lb[2*jp+1];
      pk[jp] = (unsigned int)f2bf(a) | ((unsigned int)f2bf(bqv) << 16);
    }
    int e = (((T>>4)*6 + (cg>>2))*64 + (cg&3)*16 + (T&15))*8;
    uint4 pv; pv.x = pk[0]; pv.y = pk[1]; pv.z = pk[2]; pv.w = pk[3];
    *(uint4*)(dst + e) = pv;
  }
}

// ---------------------------------------------------------------------------
// Kernel 4: MLP (bf16 MFMA) per active cell: ln(64x192) @ w1 -> gelu -> @ w2,
// *gamma + b2, store channels-first. Hidden chunked 6x128; h round-trips
// through LDS in A-fragment order.
// ---------------------------------------------------------------------------
__global__ __launch_bounds__(256, 2) void mlp_kernel(
    const unsigned short* __restrict__ lnA, const unsigned short* __restrict__ b1f,
    const unsigned short* __restrict__ b2f, const float* __restrict__ b1,
    const float* __restrict__ b2, const float* __restrict__ gamma,
    const int* __restrict__ mask, float* __restrict__ out)
{
  int bid = blockIdx.x;
  if (mask[bid] == 0) return;
  int b = bid >> 9, cell = bid & 511;
  int cz = cell >> 6, cy = (cell >> 3) & 7, cx = cell & 7;
  int z0 = cz*4, y0 = cy*4, x0 = cx*4;
  int tid = threadIdx.x, wave = tid >> 6, lane = tid & 63;
  int lq = lane >> 4, ln15 = lane & 15;

  __shared__ unsigned short hbuf[2][8192];   // 2 x 16 KB, A-frag order

  const unsigned short* Abase = lnA + (size_t)bid*12288;
  bf8v A[4][6];
  #pragma unroll
  for (int mt = 0; mt < 4; ++mt)
    #pragma unroll
    for (int ks = 0; ks < 6; ++ks)
      A[mt][ks] = *(const bf8v*)(Abase + ((mt*6 + ks)*64 + lane)*8);

  f4v acc2[4][3];
  #pragma unroll
  for (int mt = 0; mt < 4; ++mt)
    #pragma unroll
    for (int nt = 0; nt < 3; ++nt)
      acc2[mt][nt] = (f4v){0.f, 0.f, 0.f, 0.f};

  for (int ch = 0; ch < 6; ++ch) {
    f4v acc1[4][2];
    #pragma unroll
    for (int mt = 0; mt < 4; ++mt)
      #pragma unroll
      for (int jj = 0; jj < 2; ++jj)
        acc1[mt][jj] = (f4v){0.f, 0.f, 0.f, 0.f};
    #pragma unroll
    for (int ks = 0; ks < 6; ++ks) {
      #pragma unroll
      for (int jj = 0; jj < 2; ++jj) {
        int nt = ch*8 + wave*2 + jj;
        bf8v Bf = *(const bf8v*)(b1f + ((nt*6 + ks)*64 + lane)*8);
        #pragma unroll
        for (int mt = 0; mt < 4; ++mt)
          acc1[mt][jj] = __builtin_amdgcn_mfma_f32_16x16x32_bf16(A[mt][ks], Bf, acc1[mt][jj], 0, 0, 0);
      }
    }
    unsigned short* hb = hbuf[ch & 1];
    #pragma unroll
    for (int jj = 0; jj < 2; ++jj) {
      float b1v = b1[(ch*8 + wave*2 + jj)*16 + ln15];
      int lane_hi = jj*2 + (ln15 >> 3);
      #pragma unroll
      for (int mt = 0; mt < 4; ++mt)
        #pragma unroll
        for (int r = 0; r < 4; ++r) {
          float g = gelu_f(acc1[mt][jj][r] + b1v);
          int elem = ((mt*4 + wave)*64 + lane_hi*16 + (lq*4 + r))*8 + (lane & 7);
          hb[elem] = f2bf(g);
        }
    }
    __syncthreads();
    #pragma unroll
    for (int ks2 = 0; ks2 < 4; ++ks2) {
      bf8v A2[4];
      #pragma unroll
      for (int mt = 0; mt < 4; ++mt)
        A2[mt] = *(const bf8v*)(hb + ((mt*4 + ks2)*64 + lane)*8);
      #pragma unroll
      for (int nt = 0; nt < 3; ++nt) {
        int ntg = wave*3 + nt;
        int ksg = ch*4 + ks2;
        bf8v B2 = *(const bf8v*)(b2f + ((ntg*24 + ksg)*64 + lane)*8);
        #pragma unroll
        for (int mt = 0; mt < 4; ++mt)
          acc2[mt][nt] = __builtin_amdgcn_mfma_f32_16x16x32_bf16(A2[mt], B2, acc2[mt][nt], 0, 0, 0);
      }
    }
  }

  #pragma unroll
  for (int nt = 0; nt < 3; ++nt) {
    int c = (wave*3 + nt)*16 + ln15;
    float gm = gamma[c], bb = b2[c];
    size_t cbase = ((size_t)(b*CCH + c))*NPOS;
    #pragma unroll
    for (int mt = 0; mt < 4; ++mt) {
      #pragma unroll
      for (int r = 0; r < 4; ++r) {
        float vv = gm*(acc2[mt][nt][r] + bb);
        out[cbase + (size_t)(z0 + mt)*1024 + (y0 + lq)*32 + x0 + r] = vv;
      }
    }
  }
}

// ---------------------------------------------------------------------------
extern "C" void kernel_launch(void* const* d_in, const int* in_sizes, int n_in,
                              void* d_out, int out_size, void* d_ws, size_t ws_size,
                              hipStream_t stream) {
  const float* x     = (const float*)d_in[0];
  const int*   mask  = (const int*)  d_in[1];
  const float* dw_w  = (const float*)d_in[2];
  const float* dw_b  = (const float*)d_in[3];
  const float* ln_w  = (const float*)d_in[4];
  const float* ln_b  = (const float*)d_in[5];
  const float* w1    = (const float*)d_in[6];
  const float* b1    = (const float*)d_in[7];
  const float* w2    = (const float*)d_in[8];
  const float* b2    = (const float*)d_in[9];
  const float* gamma = (const float*)d_in[10];
  float* out = (float*)d_out;
  char* ws = (char*)d_ws;

  unsigned short* yb  = (unsigned short*)(ws + WS_Y);
  unsigned short* b1f = (unsigned short*)(ws + WS_B1F);
  unsigned short* b2f = (unsigned short*)(ws + WS_B2F);
  unsigned short* lnA = (unsigned short*)(ws + WS_LNA);

  conv_dw_kernel<<<768, 256, 0, stream>>>(x, dw_w, dw_b, yb);
  prep_w_kernel<<<144, 256, 0, stream>>>(w1, w2, b1f, b2f);
  ln_kernel<<<1024, 384, 0, stream>>>(yb, ln_w, ln_b, mask, lnA, out);
  mlp_kernel<<<1024, 256, 0, stream>>>(lnA, b1f, b2f, b1, b2, gamma, mask, out);
}

// Round 3
// 383.933 us; speedup vs baseline: 1.9242x; 1.9242x over previous
//
#include <hip/hip_runtime.h>
#include <hip/hip_bf16.h>

typedef __attribute__((ext_vector_type(4))) float f4v;
typedef __attribute__((ext_vector_type(8))) short bf8v;

// ---- problem constants ----
#define NPOS 32768            // 32*32*32
#define CCH  192
#define HID  768

// ---- workspace layout (bytes) ----
#define WS_Y    ((size_t)0)           // 2*512*192*64*2 = 25,165,824  conv out bf16, cell layout
#define WS_B1F  ((size_t)25165824)    // 294,912  w1 bf16 B-frag swizzled
#define WS_B2F  ((size_t)25460736)    // 294,912  w2 bf16 B-frag swizzled
// total: 25,755,648 bytes

__device__ inline unsigned short f2bf(float f){
  unsigned int u = __float_as_uint(f);
  u += 0x7FFFu + ((u >> 16) & 1u);      // RNE
  return (unsigned short)(u >> 16);
}
__device__ inline float bf2f(unsigned short s){
  return __uint_as_float(((unsigned int)s) << 16);
}
__device__ inline float gelu_f(float x){
  float u = 0.7978845608028654f * x * fmaf(0.044715f, x*x, 1.0f);
  float e = __expf(2.0f*u);
  float th = __fdividef(e - 1.0f, e + 1.0f);
  return 0.5f*x*(1.0f + th);
}

// ---------------------------------------------------------------------------
// Kernel 1: depthwise 7x7x7 conv + bias. Block = (b, c, 16x16 xy quadrant,
// 16-z half). Whole input column (22 slices x 22 rows x 24 floats, zero-padded
// halos) staged to LDS once; ONE barrier; then pure FMA with SGPR weights.
// Thread = 4dx x 4dy x 1z. Output: bf16 in cell-blocked layout
// yc[((b*512+cell)*192+c)*64 + tok], cell = cz*64+cy*8+cx, tok = (z&3)*16+(y&3)*4+(x&3).
// LDS bank note: slice stride 528, row stride 24 -> superbank = 4*(zl&1)+px
// (uniform 8 lanes per 16B group, conflict-free).
// ---------------------------------------------------------------------------
__global__ __launch_bounds__(256) void conv_dw_kernel(
    const float* __restrict__ x, const float* __restrict__ dw_w,
    const float* __restrict__ dw_b, unsigned short* __restrict__ yc)
{
  __shared__ float ring[22*528];       // 46,464 B

  int bid = blockIdx.x;                // 3072 = 192c * 16(r)
  int c = bid % 192;
  int r = bid / 192;                   // 0..15
  int xq = r & 1, yq = (r >> 1) & 1, zh = (r >> 2) & 1, b = r >> 3;
  int tx0 = xq*16, ty0 = yq*16, zb = zh*16;

  int tid = threadIdx.x;
  const float* xsrc = x + ((size_t)(b*CCH + c))*NPOS;

  // ---- stage column: 22 slices x 22 rows x 6 aligned f4 chunks = 2904
  for (int idx = tid; idx < 2904; idx += 256) {
    int sl = idx / 132;
    int rem = idx - sl*132;
    int rr = rem / 6, ci = rem - rr*6;
    int zi = zb - 3 + sl, gy = ty0 - 3 + rr, gx = tx0 - 4 + 4*ci;
    f4v v = {0.f, 0.f, 0.f, 0.f};
    if ((unsigned)zi < 32u && (unsigned)gy < 32u && (unsigned)gx <= 28u)
      v = *(const f4v*)(xsrc + (size_t)zi*1024 + gy*32 + gx);
    *(f4v*)(ring + sl*528 + rr*24 + ci*4) = v;
  }
  __syncthreads();

  int p = tid & 15, zl = tid >> 4;     // 16 patches, 16 z-planes
  int px = p & 3, py = p >> 2;
  int y0 = py*4, px4 = px*4;
  const float* base = ring + zl*528 + y0*24 + px4;
  const float* wq = dw_w + c*343;      // wave-uniform -> s_load

  float acc[16];
  #pragma unroll
  for (int i = 0; i < 16; ++i) acc[i] = 0.f;

  #pragma unroll 1                     // keep body in I-cache (~7 KB)
  for (int s = 0; s < 7; ++s) {
    float wl[49];
    #pragma unroll
    for (int i = 0; i < 49; ++i) wl[i] = wq[s*49 + i];
    const float* sb = base + s*528;
    #pragma unroll
    for (int rr = 0; rr < 10; ++rr) {
      f4v r0 = *(const f4v*)(sb + rr*24);
      f4v r1 = *(const f4v*)(sb + rr*24 + 4);
      f4v r2 = *(const f4v*)(sb + rr*24 + 8);
      float row[12];
      row[0]=r0[0]; row[1]=r0[1]; row[2]=r0[2]; row[3]=r0[3];
      row[4]=r1[0]; row[5]=r1[1]; row[6]=r1[2]; row[7]=r1[3];
      row[8]=r2[0]; row[9]=r2[1]; row[10]=r2[2]; row[11]=r2[3];
      #pragma unroll
      for (int dy = 0; dy < 4; ++dy) {
        int ky = rr - dy;
        if (ky < 0 || ky > 6) continue;          // compile-time pruned
        #pragma unroll
        for (int kx = 0; kx < 7; ++kx) {
          float w = wl[ky*7 + kx];
          #pragma unroll
          for (int dx = 0; dx < 4; ++dx)
            acc[dy*4 + dx] = fmaf(w, row[dx + kx + 1], acc[dy*4 + dx]);
        }
      }
    }
  }

  // ---- store bf16 to cell-blocked layout
  float bias = dw_b[c];
  int z = zb + zl;
  int cz = z >> 2, cx = (tx0 >> 2) + px, cy = (ty0 >> 2) + py;
  int cell = cz*64 + cy*8 + cx;
  unsigned short* ybase = yc + (((size_t)(b*512 + cell))*192 + c)*64;
  int tokz = (z & 3)*16;
  #pragma unroll
  for (int dy = 0; dy < 4; ++dy) {
    ushort4 o;
    o.x = f2bf(acc[dy*4+0] + bias);
    o.y = f2bf(acc[dy*4+1] + bias);
    o.z = f2bf(acc[dy*4+2] + bias);
    o.w = f2bf(acc[dy*4+3] + bias);
    *(ushort4*)(ybase + tokz + dy*4) = o;
  }
}

// ---------------------------------------------------------------------------
// Kernel 2: weight prep. w1/w2 -> bf16 MFMA-B-fragment order.
// B-frag (16x16x32): element (k,n) -> lane=((k%32)/8)*16+(n%16), byte j=k%8.
// ---------------------------------------------------------------------------
__global__ __launch_bounds__(256) void prep_w_kernel(
    const float* __restrict__ w1, const float* __restrict__ w2,
    unsigned short* __restrict__ b1f, unsigned short* __restrict__ b2f)
{
  int gid = blockIdx.x*256 + threadIdx.x;
  if (gid < 18432) {
    int fi = gid;                         // w1 (C=192 x HID=768)
    int lane = fi & 63, fr = fi >> 6;
    int nt = fr / 6, ks = fr - nt*6;
    int n  = nt*16 + (lane & 15);
    int kb = ks*32 + (lane >> 4)*8;
    #pragma unroll
    for (int j = 0; j < 8; ++j) b1f[fi*8 + j] = f2bf(w1[(kb+j)*HID + n]);
  } else if (gid < 36864) {
    int fi = gid - 18432;                 // w2 (HID=768 x C=192)
    int lane = fi & 63, fr = fi >> 6;
    int nt = fr / 24, ks = fr - nt*24;
    int n  = nt*16 + (lane & 15);
    int kb = ks*32 + (lane >> 4)*8;
    #pragma unroll
    for (int j = 0; j < 8; ++j) b2f[fi*8 + j] = f2bf(w2[(kb+j)*CCH + n]);
  }
}

// ---------------------------------------------------------------------------
// Kernel 3: fused LN + MLP per active cell. Reads yc (cell layout, contiguous
// 24.6 KB/block), computes LN stats + A-fragments in-block, then
// A(64x192) @ w1 -> gelu -> @ w2, *gamma + b2, f4v store channels-first.
// Inactive cells: zero-fill out. LDS ~46.6 KB.
// ---------------------------------------------------------------------------
__global__ __launch_bounds__(256) void mlp_kernel(
    const unsigned short* __restrict__ yc, const unsigned short* __restrict__ b1f,
    const unsigned short* __restrict__ b2f, const float* __restrict__ b1,
    const float* __restrict__ b2, const float* __restrict__ gamma,
    const float* __restrict__ ln_w, const float* __restrict__ ln_b,
    const int* __restrict__ mask, float* __restrict__ out)
{
  int bid = blockIdx.x;
  int b = bid >> 9, cell = bid & 511;
  int cz = cell >> 6, cy = (cell >> 3) & 7, cx = cell & 7;
  int z0 = cz*4, y0 = cy*4, x0 = cx*4;
  int tid = threadIdx.x, wave = tid >> 6, lane = tid & 63;
  int lq = lane >> 4, ln15 = lane & 15;

  if (mask[bid] == 0) {
    f4v z4 = {0.f, 0.f, 0.f, 0.f};
    #pragma unroll
    for (int pp = 0; pp < 12; ++pp) {
      int i4 = tid + 256*pp;              // 0..3071
      int c = i4 >> 4, rem = i4 & 15;
      int dz = rem >> 2, dy = rem & 3;
      *(f4v*)(out + ((size_t)(b*CCH + c))*NPOS
                  + (size_t)(z0+dz)*1024 + (y0+dy)*32 + x0) = z4;
    }
    return;
  }

  __shared__ unsigned short ymat[192*68];   // stride 68 (conflict-free)
  __shared__ float sred[2][4][64];
  __shared__ float murs[2][64];
  __shared__ float lnwb[2][192];
  __shared__ unsigned short hbuf[8192];     // 16 KB, A2-frag order

  // ---- stage yc -> ymat (8B aligned: 136c + 8*t4)
  const unsigned short* ysrc = yc + (size_t)bid*12288;
  #pragma unroll
  for (int k = 0; k < 12; ++k) {
    int idx = tid + 256*k;                  // 0..3071
    int c = idx >> 4, t4 = idx & 15;
    *(ushort4*)(ymat + c*68 + t4*4) = *(const ushort4*)(ysrc + c*64 + t4*4);
  }
  if (tid < 192) { lnwb[0][tid] = ln_w[tid]; lnwb[1][tid] = ln_b[tid]; }
  __syncthreads();

  // ---- LN stats: thread (tok = tid&63, part = tid>>6) sums 48 channels
  {
    int tok = tid & 63, part = tid >> 6;
    float S = 0.f, Q = 0.f;
    #pragma unroll
    for (int j = 0; j < 48; ++j) {
      float v = bf2f(ymat[(part*48 + j)*68 + tok]);
      S += v; Q = fmaf(v, v, Q);
    }
    sred[0][part][tok] = S; sred[1][part][tok] = Q;
  }
  __syncthreads();
  if (tid < 64) {
    float S = sred[0][0][tid] + sred[0][1][tid] + sred[0][2][tid] + sred[0][3][tid];
    float Q = sred[1][0][tid] + sred[1][1][tid] + sred[1][2][tid] + sred[1][3][tid];
    float m = S*(1.f/192.f);
    float var = Q*(1.f/192.f) - m*m;
    murs[0][tid] = m;
    murs[1][tid] = rsqrtf(var + 1e-6f);
  }
  __syncthreads();

  // ---- build A-fragments in registers (layout matches validated elem formula)
  bf8v A[4][6];
  #pragma unroll
  for (int mt = 0; mt < 4; ++mt) {
    int tok = mt*16 + ln15;
    float m = murs[0][tok], rs = murs[1][tok];
    #pragma unroll
    for (int ks = 0; ks < 6; ++ks) {
      int c0 = ks*32 + lq*8;
      union { bf8v v; unsigned short u[8]; } pk;
      #pragma unroll
      for (int j = 0; j < 8; ++j) {
        int cc = c0 + j;
        float v = (bf2f(ymat[cc*68 + tok]) - m)*rs*lnwb[0][cc] + lnwb[1][cc];
        pk.u[j] = f2bf(v);
      }
      A[mt][ks] = pk.v;
    }
  }

  f4v acc2[4][3];
  #pragma unroll
  for (int mt = 0; mt < 4; ++mt)
    #pragma unroll
    for (int nt = 0; nt < 3; ++nt)
      acc2[mt][nt] = (f4v){0.f, 0.f, 0.f, 0.f};

  for (int ch = 0; ch < 6; ++ch) {
    // ---- GEMM1: h[:, ch*128 .. +128); wave owns ntiles ch*8+wave*2+{0,1}
    f4v acc1[4][2];
    #pragma unroll
    for (int mt = 0; mt < 4; ++mt)
      #pragma unroll
      for (int jj = 0; jj < 2; ++jj)
        acc1[mt][jj] = (f4v){0.f, 0.f, 0.f, 0.f};
    #pragma unroll
    for (int ks = 0; ks < 6; ++ks) {
      #pragma unroll
      for (int jj = 0; jj < 2; ++jj) {
        int nt = ch*8 + wave*2 + jj;
        bf8v Bf = *(const bf8v*)(b1f + ((nt*6 + ks)*64 + lane)*8);
        #pragma unroll
        for (int mt = 0; mt < 4; ++mt)
          acc1[mt][jj] = __builtin_amdgcn_mfma_f32_16x16x32_bf16(A[mt][ks], Bf, acc1[mt][jj], 0, 0, 0);
      }
    }
    // ---- bias + gelu -> hbuf (A2-frag order; ks2 slot = this wave)
    #pragma unroll
    for (int jj = 0; jj < 2; ++jj) {
      float b1v = b1[(ch*8 + wave*2 + jj)*16 + ln15];
      int lane_hi = jj*2 + (ln15 >> 3);
      #pragma unroll
      for (int mt = 0; mt < 4; ++mt)
        #pragma unroll
        for (int rr = 0; rr < 4; ++rr) {
          float g = gelu_f(acc1[mt][jj][rr] + b1v);
          int elem = ((mt*4 + wave)*64 + lane_hi*16 + (lq*4 + rr))*8 + (lane & 7);
          hbuf[elem] = f2bf(g);
        }
    }
    __syncthreads();
    // ---- GEMM2 partial: out += h_chunk @ w2[ch*128.., :]
    #pragma unroll
    for (int ks2 = 0; ks2 < 4; ++ks2) {
      bf8v A2[4];
      #pragma unroll
      for (int mt = 0; mt < 4; ++mt)
        A2[mt] = *(const bf8v*)(hbuf + ((mt*4 + ks2)*64 + lane)*8);
      #pragma unroll
      for (int nt = 0; nt < 3; ++nt) {
        int ntg = wave*3 + nt;
        int ksg = ch*4 + ks2;
        bf8v B2 = *(const bf8v*)(b2f + ((ntg*24 + ksg)*64 + lane)*8);
        #pragma unroll
        for (int mt = 0; mt < 4; ++mt)
          acc2[mt][nt] = __builtin_amdgcn_mfma_f32_16x16x32_bf16(A2[mt], B2, acc2[mt][nt], 0, 0, 0);
      }
    }
    __syncthreads();
  }

  // ---- epilogue: gamma*(acc+b2), f4v store channels-first (x0..x0+3 = regs)
  #pragma unroll
  for (int nt = 0; nt < 3; ++nt) {
    int c = (wave*3 + nt)*16 + ln15;
    float gm = gamma[c], bb = b2[c];
    size_t cbase = ((size_t)(b*CCH + c))*NPOS + (size_t)(y0 + lq)*32 + x0;
    #pragma unroll
    for (int mt = 0; mt < 4; ++mt) {
      f4v o;
      o[0] = gm*(acc2[mt][nt][0] + bb);
      o[1] = gm*(acc2[mt][nt][1] + bb);
      o[2] = gm*(acc2[mt][nt][2] + bb);
      o[3] = gm*(acc2[mt][nt][3] + bb);
      *(f4v*)(out + cbase + (size_t)(z0 + mt)*1024) = o;
    }
  }
}

// ---------------------------------------------------------------------------
extern "C" void kernel_launch(void* const* d_in, const int* in_sizes, int n_in,
                              void* d_out, int out_size, void* d_ws, size_t ws_size,
                              hipStream_t stream) {
  const float* x     = (const float*)d_in[0];
  const int*   mask  = (const int*)  d_in[1];
  const float* dw_w  = (const float*)d_in[2];
  const float* dw_b  = (const float*)d_in[3];
  const float* ln_w  = (const float*)d_in[4];
  const float* ln_b  = (const float*)d_in[5];
  const float* w1    = (const float*)d_in[6];
  const float* b1    = (const float*)d_in[7];
  const float* w2    = (const float*)d_in[8];
  const float* b2    = (const float*)d_in[9];
  const float* gamma = (const float*)d_in[10];
  float* out = (float*)d_out;
  char* ws = (char*)d_ws;

  unsigned short* yc  = (unsigned short*)(ws + WS_Y);
  unsigned short* b1f = (unsigned short*)(ws + WS_B1F);
  unsigned short* b2f = (unsigned short*)(ws + WS_B2F);

  conv_dw_kernel<<<3072, 256, 0, stream>>>(x, dw_w, dw_b, yc);
  prep_w_kernel<<<144, 256, 0, stream>>>(w1, w2, b1f, b2f);
  mlp_kernel<<<1024, 256, 0, stream>>>(yc, b1f, b2f, b1, b2, gamma, ln_w, ln_b, mask, out);
}